// Round 8
// baseline (138.523 us; speedup 1.0000x reference)
//
#include <hip/hip_runtime.h>
#include <stdint.h>

#define S_ 512
#define B_ 32
#define D_ 256
#define XSZ ((int64_t)B_ * S_ * D_)

typedef __attribute__((ext_vector_type(8))) short bf16x8;
typedef __attribute__((ext_vector_type(4))) float f32x4;

#define WAITVM(n) asm volatile("s_waitcnt vmcnt(" #n ")" ::: "memory")
#define SCHEDB() __builtin_amdgcn_sched_barrier(0)
#define BAR() __builtin_amdgcn_s_barrier()

__device__ __forceinline__ unsigned short f2bf(float f) {
    union { float f; uint32_t u; } v; v.f = f;
    uint32_t r = v.u + 0x7FFFu + ((v.u >> 16) & 1u);
    return (unsigned short)(r >> 16);
}
__device__ __forceinline__ uint32_t pk2(float a, float b) {
    return (uint32_t)f2bf(a) | ((uint32_t)f2bf(b) << 16);
}

__device__ __forceinline__ void gl_lds16(const unsigned short* g, void* lds_base) {
    __builtin_amdgcn_global_load_lds(
        (const __attribute__((address_space(1))) unsigned int*)g,
        (__attribute__((address_space(3))) unsigned int*)lds_base, 16, 0, 0);
}

__device__ __forceinline__ f32x4 MF(bf16x8 a, bf16x8 b, f32x4 c) {
    return __builtin_amdgcn_mfma_f32_16x16x32_bf16(a, b, c, 0, 0, 0);
}

// ---------- fused prep: [0,12288) adj  [12288,13312) xT  [13312,13696) W ----------
__global__ __launch_bounds__(256) void prep_kernel(
    const float* __restrict__ adj, const float* __restrict__ gcn,
    const float* __restrict__ W, const float* __restrict__ Wout,
    unsigned short* __restrict__ adjBf, float* __restrict__ dInv,
    unsigned short* __restrict__ XbfT,
    unsigned short* __restrict__ Wbf, unsigned short* __restrict__ WoutBf)
{
    __shared__ unsigned short T[64 * 65];
    const int bx = blockIdx.x;
    const int tid = threadIdx.x;

    if (bx < 12288) {  // ---- adj: bf16 + I, dInv ----
        const int flat = bx * 4 + (tid >> 6);
        const int lane = tid & 63;
        const float* src = adj + (int64_t)flat * S_ + lane * 8;
        float4 v0 = ((const float4*)src)[0];
        float4 v1 = ((const float4*)src)[1];
        float sum = v0.x + v0.y + v0.z + v0.w + v1.x + v1.y + v1.z + v1.w;
#pragma unroll
        for (int o = 1; o < 64; o <<= 1) sum += __shfl_xor(sum, o);
        const int s = flat & (S_ - 1);
        const int c0 = lane * 8;
        float e0 = v0.x + ((s == c0 + 0) ? 1.f : 0.f);
        float e1 = v0.y + ((s == c0 + 1) ? 1.f : 0.f);
        float e2 = v0.z + ((s == c0 + 2) ? 1.f : 0.f);
        float e3 = v0.w + ((s == c0 + 3) ? 1.f : 0.f);
        float e4 = v1.x + ((s == c0 + 4) ? 1.f : 0.f);
        float e5 = v1.y + ((s == c0 + 5) ? 1.f : 0.f);
        float e6 = v1.z + ((s == c0 + 6) ? 1.f : 0.f);
        float e7 = v1.w + ((s == c0 + 7) ? 1.f : 0.f);
        uint4 p;
        p.x = pk2(e0, e1); p.y = pk2(e2, e3);
        p.z = pk2(e4, e5); p.w = pk2(e6, e7);
        *(uint4*)&adjBf[(int64_t)flat * S_ + c0] = p;
        if (lane == 0) dInv[flat] = 1.0f / (sum + 1.0f);
    } else if (bx < 13312) {  // ---- gcn -> XbfT (transpose) ----
        const int idx = bx - 12288;
        const int s0 = (idx & 7) * 64, d0 = ((idx >> 3) & 3) * 64, b = idx >> 5;
        const int r = tid >> 2, seg = tid & 3;
        const float* src = gcn + ((int64_t)(b * S_ + s0 + r)) * D_ + d0 + seg * 16;
#pragma unroll
        for (int q = 0; q < 4; q++) {
            float4 v = ((const float4*)src)[q];
            unsigned short* t = &T[r * 65 + seg * 16 + q * 4];
            t[0] = f2bf(v.x); t[1] = f2bf(v.y); t[2] = f2bf(v.z); t[3] = f2bf(v.w);
        }
        __syncthreads();
        unsigned short tmp[16];
#pragma unroll
        for (int j = 0; j < 16; j++) tmp[j] = T[(seg * 16 + j) * 65 + r];
        unsigned short* dst = &XbfT[((int64_t)(b * D_ + d0 + r)) * S_ + s0 + seg * 16];
        ((uint4*)dst)[0] = ((uint4*)tmp)[0];
        ((uint4*)dst)[1] = ((uint4*)tmp)[1];
    } else {  // ---- W, Wout -> bf16 ----
        const int i = ((bx - 13312) * 256 + tid) * 4;
        {
            float4 v = *(const float4*)&W[i];
            uint2 p; p.x = pk2(v.x, v.y); p.y = pk2(v.z, v.w);
            *(uint2*)&Wbf[i] = p;
        }
        {
            float4 v = *(const float4*)&Wout[i];
            uint2 p; p.x = pk2(v.x, v.y); p.y = pk2(v.z, v.w);
            *(uint2*)&WoutBf[i] = p;
        }
    }
}

// ---------- layers (all 3 heads, one l): 768 blocks, 4 waves, tile 64s x 256d ----------
// bmm BK=64 (8 steps, 32 MFMA : 10 loads per wave, counted vmcnt).
// mm2 BK=32 (8 steps): Ps in LDS, W direct from global (2-deep reg prefetch, no barriers).
template<int L>
__global__ __launch_bounds__(256, 2) void layers_kernel(
    const unsigned short* __restrict__ adjBf,  // [3][B][S][S] (diag+1)
    const unsigned short* __restrict__ XbfT,   // [B][D][S]        (L==0 input)
    unsigned short* __restrict__ yTh,          // [3][B][D][S]     (L==0 out / L==1 in)
    const unsigned short* __restrict__ Wbf,    // [6][D][D]
    const float* __restrict__ bvec,            // [6][D]
    const float* __restrict__ dInv,            // [3][B][S]
    unsigned short* __restrict__ yAll)         // [6][B][S][D]
{
    __shared__ __align__(16) char smem[81920];
    // bmm: bufA = smem + cur*8192 (64x128B), bufB = smem + 16384 + cur*32768 (256x128B)
    // overlay after bmm: Ps = smem[0..33792) (264-stride rows); Dsh @ 69632

    const int tid = threadIdx.x;
    const int w   = tid >> 6;
    const int l   = tid & 63;
    const int lm  = l & 15;
    const int g   = l >> 4;

    int flat = blockIdx.x;
    flat = (flat & 7) * 96 + (flat >> 3);      // XCD-chunked (768 = 8*96, bijective)
    const int h  = flat >> 8;
    const int rem = flat & 255;
    const int b  = rem >> 3;
    const int s0 = (rem & 7) * 64;

    const unsigned short* adjB = adjBf + (((int64_t)h * B_ + b) * S_ + s0) * S_;
    const unsigned short* xTB  = (L == 0) ? (XbfT + (int64_t)b * D_ * S_)
                                          : (yTh + ((int64_t)h * B_ + b) * D_ * S_);
    const unsigned short* Wl   = Wbf + (int64_t)(h * 2 + L) * D_ * D_;
    const float* bl            = bvec + (h * 2 + L) * D_;
    const float* dInvB         = dInv + ((int64_t)h * B_ + b) * S_ + s0;
    unsigned short* y          = yAll + (int64_t)(h * 2 + L) * XSZ + ((int64_t)(b * S_ + s0)) * D_;

    const int srow8  = l >> 3;                   // row-in-8
    const int schunk = ((l & 7) ^ (l >> 3)) * 8; // pre-swizzled source col (shorts)

    f32x4 acc[4][4];
#pragma unroll
    for (int i = 0; i < 4; i++)
#pragma unroll
        for (int j = 0; j < 4; j++) acc[i][j] = (f32x4){0.f, 0.f, 0.f, 0.f};

    auto stage = [&](int t0, int cur) {          // 10 gl_lds per wave
        char* bA = smem + cur * 8192;
        char* bB = smem + 16384 + cur * 32768;
        gl_lds16(&adjB[(w * 16 + srow8) * S_ + t0 + schunk], bA + w * 2048);
        gl_lds16(&adjB[(w * 16 + 8 + srow8) * S_ + t0 + schunk], bA + w * 2048 + 1024);
#pragma unroll
        for (int j = 0; j < 8; j++)
            gl_lds16(&xTB[(int64_t)(w * 64 + j * 8 + srow8) * S_ + t0 + schunk],
                     bB + w * 8192 + j * 1024);
    };
    auto compute = [&](int cur) {
        const char* bA = smem + cur * 8192;
        const char* bB = smem + 16384 + cur * 32768;
        __builtin_amdgcn_s_setprio(1);
#pragma unroll
        for (int h2 = 0; h2 < 2; h2++) {
            const int co = ((h2 * 4 + g) ^ (lm & 7)) * 16;
            bf16x8 aF[4];
#pragma unroll
            for (int mi = 0; mi < 4; mi++)
                aF[mi] = *(const bf16x8*)(bA + (mi * 16 + lm) * 128 + co);
#pragma unroll
            for (int ni = 0; ni < 4; ni++) {
                bf16x8 bF = *(const bf16x8*)(bB + (w * 64 + ni * 16 + lm) * 128 + co);
#pragma unroll
                for (int mi = 0; mi < 4; mi++)
                    acc[mi][ni] = MF(aF[mi], bF, acc[mi][ni]);
            }
        }
        __builtin_amdgcn_s_setprio(0);
    };

    // ---- bmm: P = (A+I)x ----
    stage(0, 0);
    for (int t = 0; t < 8; t++) {
        const int cur = t & 1;
        if (t < 7) { stage((t + 1) * 64, cur ^ 1); WAITVM(10); }
        else       { WAITVM(0); }
        SCHEDB(); BAR(); SCHEDB();
        compute(cur);
        SCHEDB(); BAR();
    }

    // ---- P -> Ps (bf16) ----
    unsigned short* Ps = (unsigned short*)smem;
#pragma unroll
    for (int mi = 0; mi < 4; mi++)
#pragma unroll
        for (int ni = 0; ni < 4; ni++) {
            const int col = w * 64 + ni * 16 + lm;
#pragma unroll
            for (int r = 0; r < 4; r++)
                Ps[(mi * 16 + g * 4 + r) * 264 + col] = f2bf(acc[mi][ni][r]);
        }
    __syncthreads();

    // ---- mm2: Q = P @ W^T ; W frags direct from global, 2-deep prefetch, no barriers ----
    f32x4 acc2[4][4];
#pragma unroll
    for (int i = 0; i < 4; i++)
#pragma unroll
        for (int j = 0; j < 4; j++) acc2[i][j] = (f32x4){0.f, 0.f, 0.f, 0.f};

    const unsigned short* wb0 = Wl + (w * 64 + 0 * 16 + lm) * D_ + g * 8;
    const unsigned short* wb1 = Wl + (w * 64 + 1 * 16 + lm) * D_ + g * 8;
    const unsigned short* wb2 = Wl + (w * 64 + 2 * 16 + lm) * D_ + g * 8;
    const unsigned short* wb3 = Wl + (w * 64 + 3 * 16 + lm) * D_ + g * 8;
    bf16x8 wv0[4], wv1[4];
    wv0[0] = *(const bf16x8*)(wb0);      wv0[1] = *(const bf16x8*)(wb1);
    wv0[2] = *(const bf16x8*)(wb2);      wv0[3] = *(const bf16x8*)(wb3);
    wv1[0] = *(const bf16x8*)(wb0 + 32); wv1[1] = *(const bf16x8*)(wb1 + 32);
    wv1[2] = *(const bf16x8*)(wb2 + 32); wv1[3] = *(const bf16x8*)(wb3 + 32);

#pragma unroll
    for (int kc = 0; kc < 8; kc++) {
        bf16x8 aF[4];
#pragma unroll
        for (int mi = 0; mi < 4; mi++)
            aF[mi] = *(const bf16x8*)&Ps[(mi * 16 + lm) * 264 + kc * 32 + g * 8];
        __builtin_amdgcn_s_setprio(1);
#pragma unroll
        for (int ni = 0; ni < 4; ni++) {
            bf16x8 bF = (kc & 1) ? wv1[ni] : wv0[ni];
#pragma unroll
            for (int mi = 0; mi < 4; mi++)
                acc2[mi][ni] = MF(aF[mi], bF, acc2[mi][ni]);
        }
        __builtin_amdgcn_s_setprio(0);
        if (kc + 2 < 8) {
            const int off = (kc + 2) * 32;
            if (kc & 1) {
                wv1[0] = *(const bf16x8*)(wb0 + off); wv1[1] = *(const bf16x8*)(wb1 + off);
                wv1[2] = *(const bf16x8*)(wb2 + off); wv1[3] = *(const bf16x8*)(wb3 + off);
            } else {
                wv0[0] = *(const bf16x8*)(wb0 + off); wv0[1] = *(const bf16x8*)(wb1 + off);
                wv0[2] = *(const bf16x8*)(wb2 + off); wv0[3] = *(const bf16x8*)(wb3 + off);
            }
        }
    }
    __syncthreads();   // all Ps reads retired before epilogue overwrite

    // ---- epilogue: y = relu((Q + 2b) * dInv) ----
    float dv[4][4];
#pragma unroll
    for (int mi = 0; mi < 4; mi++)
#pragma unroll
        for (int r = 0; r < 4; r++)
            dv[mi][r] = dInvB[mi * 16 + g * 4 + r];

#pragma unroll
    for (int ni = 0; ni < 4; ni++) {
        const int col = w * 64 + ni * 16 + lm;
        const float bv = 2.0f * bl[col];
#pragma unroll
        for (int mi = 0; mi < 4; mi++)
#pragma unroll
            for (int r = 0; r < 4; r++) {
                float v = (acc2[mi][ni][r] + bv) * dv[mi][r];
                v = v > 0.f ? v : 0.f;
                Ps[(mi * 16 + g * 4 + r) * 264 + col] = f2bf(v);
            }
    }
    __syncthreads();

    // coalesced y store: 64 rows x 512B, 128B/thread
    {
        const int rr = tid >> 2, seg = (tid & 3) * 64;
        const uint4* srcp = (const uint4*)&Ps[rr * 264 + seg];
        uint4* dst = (uint4*)&y[rr * D_ + seg];
#pragma unroll
        for (int q = 0; q < 8; q++) dst[q] = srcp[q];
    }
    if (L == 0) {  // transposed yT for next layer's bmm
        unsigned short* yT = yTh + ((int64_t)h * B_ + b) * D_ * S_;
        const int e = tid;
        unsigned short tmp[64];
#pragma unroll
        for (int s = 0; s < 64; s++) tmp[s] = Ps[s * 264 + e];
        uint4* dst = (uint4*)&yT[(int64_t)e * S_ + s0];
#pragma unroll
        for (int q = 0; q < 8; q++) dst[q] = ((uint4*)tmp)[q];
    }
}

// ---------- final: 512 blocks @ 2/CU, 32s x 256e, BK=64 x24 steps ----------
__global__ __launch_bounds__(256, 2) void final_kernel(
    const unsigned short* __restrict__ yAll,
    const unsigned short* __restrict__ WoutBf,  // [256][1536]
    const float* __restrict__ gcn,
    const float* __restrict__ bout,
    float* __restrict__ out)
{
    __shared__ __align__(16) char smem[73728];

    const int tid = threadIdx.x;
    const int w   = tid >> 6;
    const int l   = tid & 63;
    const int lm  = l & 15;
    const int g   = l >> 4;

    int flat = blockIdx.x;
    flat = (flat & 7) * 64 + (flat >> 3);    // 512 = 8*64, bijective
    const int b  = flat >> 4;
    const int s0 = (flat & 15) * 32;

    const int srow8  = l >> 3;
    const int schunk = ((l & 7) ^ (l >> 3)) * 8;
    const unsigned short* yBase = yAll + (int64_t)(b * S_ + s0) * D_;

    auto stage = [&](int kc, int cur) {       // 9 gl_lds per wave
        char* bA = smem + cur * 4096;
        char* bB = smem + 8192 + cur * 32768;
        const int hl = kc >> 2;
        const int e0 = (kc & 3) * 64;
        gl_lds16(&yBase[(int64_t)hl * XSZ + (w * 8 + srow8) * D_ + e0 + schunk],
                 bA + w * 1024);
#pragma unroll
        for (int j = 0; j < 8; j++)
            gl_lds16(&WoutBf[(w * 64 + j * 8 + srow8) * 1536 + kc * 64 + schunk],
                     bB + w * 8192 + j * 1024);
    };

    f32x4 acc[2][4];
#pragma unroll
    for (int i = 0; i < 2; i++)
#pragma unroll
        for (int j = 0; j < 4; j++) acc[i][j] = (f32x4){0.f, 0.f, 0.f, 0.f};

    stage(0, 0);
    for (int t = 0; t < 24; t++) {
        const int cur = t & 1;
        if (t < 23) { stage(t + 1, cur ^ 1); WAITVM(9); }
        else        { WAITVM(0); }
        SCHEDB(); BAR(); SCHEDB();
        {
            const char* bA = smem + cur * 4096;
            const char* bB = smem + 8192 + cur * 32768;
            __builtin_amdgcn_s_setprio(1);
#pragma unroll
            for (int h2 = 0; h2 < 2; h2++) {
                const int co = (((h2 * 4 + g) ^ (lm & 7)) << 4);
                bf16x8 a0 = *(const bf16x8*)(bA + lm * 128 + co);
                bf16x8 a1 = *(const bf16x8*)(bA + (16 + lm) * 128 + co);
#pragma unroll
                for (int ni = 0; ni < 4; ni++) {
                    bf16x8 bF = *(const bf16x8*)(bB + (w * 64 + ni * 16 + lm) * 128 + co);
                    acc[0][ni] = MF(a0, bF, acc[0][ni]);
                    acc[1][ni] = MF(a1, bF, acc[1][ni]);
                }
            }
            __builtin_amdgcn_s_setprio(0);
        }
        SCHEDB(); BAR();
    }

#pragma unroll
    for (int ni = 0; ni < 4; ni++) {
        const int e = w * 64 + ni * 16 + lm;
        const float bo = bout[e];
#pragma unroll
        for (int mi = 0; mi < 2; mi++)
#pragma unroll
            for (int r = 0; r < 4; r++) {
                const int row = mi * 16 + g * 4 + r;
                const int64_t idx = ((int64_t)(b * S_ + s0 + row)) * D_ + e;
                out[idx] = acc[mi][ni][r] + gcn[idx] + bo;
            }
    }
}

extern "C" void kernel_launch(void* const* d_in, const int* in_sizes, int n_in,
                              void* d_out, int out_size, void* d_ws, size_t ws_size,
                              hipStream_t stream) {
    const float* adj  = (const float*)d_in[0];
    const float* gcn  = (const float*)d_in[1];
    const float* W    = (const float*)d_in[4];
    const float* bvec = (const float*)d_in[5];
    const float* Wout = (const float*)d_in[6];
    const float* bout = (const float*)d_in[7];
    float* out = (float*)d_out;

    const int64_t ADJ_N = (int64_t)3 * B_ * S_ * S_;
    unsigned short* adjBf  = (unsigned short*)d_ws;
    unsigned short* XbfT   = adjBf + ADJ_N;
    unsigned short* yAll   = XbfT + XSZ;        // 6 slices [B][S][D]
    unsigned short* yTh    = yAll + 6 * XSZ;    // 3 slices [B][D][S]
    unsigned short* Wbf    = yTh + 3 * XSZ;
    unsigned short* WoutBf = Wbf + 6 * D_ * D_;
    float* dInv            = (float*)(WoutBf + 6 * D_ * D_);  // [3][B][S]

    prep_kernel<<<13696, 256, 0, stream>>>(adj, gcn, W, Wout,
                                           adjBf, dInv, XbfT, Wbf, WoutBf);
    layers_kernel<0><<<768, 256, 0, stream>>>(adjBf, XbfT, yTh, Wbf, bvec, dInv, yAll);
    layers_kernel<1><<<768, 256, 0, stream>>>(adjBf, XbfT, yTh, Wbf, bvec, dInv, yAll);
    final_kernel<<<512, 256, 0, stream>>>(yAll, WoutBf, gcn, bout, out);
}

// Round 9
// 128.866 us; speedup vs baseline: 1.0749x; 1.0749x over previous
//
#include <hip/hip_runtime.h>
#include <stdint.h>

#define S_ 512
#define B_ 32
#define D_ 256
#define XSZ ((int64_t)B_ * S_ * D_)

typedef __attribute__((ext_vector_type(8))) short bf16x8;
typedef __attribute__((ext_vector_type(4))) float f32x4;

#define WAITVM(n) asm volatile("s_waitcnt vmcnt(" #n ")" ::: "memory")
#define WAITLG() asm volatile("s_waitcnt lgkmcnt(0)" ::: "memory")
#define SCHEDB() __builtin_amdgcn_sched_barrier(0)
#define BAR() __builtin_amdgcn_s_barrier()

__device__ __forceinline__ unsigned short f2bf(float f) {
    union { float f; uint32_t u; } v; v.f = f;
    uint32_t r = v.u + 0x7FFFu + ((v.u >> 16) & 1u);
    return (unsigned short)(r >> 16);
}
__device__ __forceinline__ uint32_t pk2(float a, float b) {
    return (uint32_t)f2bf(a) | ((uint32_t)f2bf(b) << 16);
}

__device__ __forceinline__ void gl_lds16(const unsigned short* g, void* lds_base) {
    __builtin_amdgcn_global_load_lds(
        (const __attribute__((address_space(1))) unsigned int*)g,
        (__attribute__((address_space(3))) unsigned int*)lds_base, 16, 0, 0);
}

__device__ __forceinline__ f32x4 MF(bf16x8 a, bf16x8 b, f32x4 c) {
    return __builtin_amdgcn_mfma_f32_16x16x32_bf16(a, b, c, 0, 0, 0);
}

// ---------- fused prep: [0,12288) adj  [12288,13312) xT  [13312,13696) W ----------
__global__ __launch_bounds__(256) void prep_kernel(
    const float* __restrict__ adj, const float* __restrict__ gcn,
    const float* __restrict__ W, const float* __restrict__ Wout,
    unsigned short* __restrict__ adjBf, float* __restrict__ dInv,
    unsigned short* __restrict__ XbfT,
    unsigned short* __restrict__ Wbf, unsigned short* __restrict__ WoutBf)
{
    __shared__ unsigned short T[64 * 65];
    const int bx = blockIdx.x;
    const int tid = threadIdx.x;

    if (bx < 12288) {  // ---- adj: bf16 + I, dInv ----
        const int flat = bx * 4 + (tid >> 6);
        const int lane = tid & 63;
        const float* src = adj + (int64_t)flat * S_ + lane * 8;
        float4 v0 = ((const float4*)src)[0];
        float4 v1 = ((const float4*)src)[1];
        float sum = v0.x + v0.y + v0.z + v0.w + v1.x + v1.y + v1.z + v1.w;
#pragma unroll
        for (int o = 1; o < 64; o <<= 1) sum += __shfl_xor(sum, o);
        const int s = flat & (S_ - 1);
        const int c0 = lane * 8;
        float e0 = v0.x + ((s == c0 + 0) ? 1.f : 0.f);
        float e1 = v0.y + ((s == c0 + 1) ? 1.f : 0.f);
        float e2 = v0.z + ((s == c0 + 2) ? 1.f : 0.f);
        float e3 = v0.w + ((s == c0 + 3) ? 1.f : 0.f);
        float e4 = v1.x + ((s == c0 + 4) ? 1.f : 0.f);
        float e5 = v1.y + ((s == c0 + 5) ? 1.f : 0.f);
        float e6 = v1.z + ((s == c0 + 6) ? 1.f : 0.f);
        float e7 = v1.w + ((s == c0 + 7) ? 1.f : 0.f);
        uint4 p;
        p.x = pk2(e0, e1); p.y = pk2(e2, e3);
        p.z = pk2(e4, e5); p.w = pk2(e6, e7);
        *(uint4*)&adjBf[(int64_t)flat * S_ + c0] = p;
        if (lane == 0) dInv[flat] = 1.0f / (sum + 1.0f);
    } else if (bx < 13312) {  // ---- gcn -> XbfT (transpose) ----
        const int idx = bx - 12288;
        const int s0 = (idx & 7) * 64, d0 = ((idx >> 3) & 3) * 64, b = idx >> 5;
        const int r = tid >> 2, seg = tid & 3;
        const float* src = gcn + ((int64_t)(b * S_ + s0 + r)) * D_ + d0 + seg * 16;
#pragma unroll
        for (int q = 0; q < 4; q++) {
            float4 v = ((const float4*)src)[q];
            unsigned short* t = &T[r * 65 + seg * 16 + q * 4];
            t[0] = f2bf(v.x); t[1] = f2bf(v.y); t[2] = f2bf(v.z); t[3] = f2bf(v.w);
        }
        __syncthreads();
        unsigned short tmp[16];
#pragma unroll
        for (int j = 0; j < 16; j++) tmp[j] = T[(seg * 16 + j) * 65 + r];
        unsigned short* dst = &XbfT[((int64_t)(b * D_ + d0 + r)) * S_ + s0 + seg * 16];
        ((uint4*)dst)[0] = ((uint4*)tmp)[0];
        ((uint4*)dst)[1] = ((uint4*)tmp)[1];
    } else {  // ---- W, Wout -> bf16 ----
        const int i = ((bx - 13312) * 256 + tid) * 4;
        {
            float4 v = *(const float4*)&W[i];
            uint2 p; p.x = pk2(v.x, v.y); p.y = pk2(v.z, v.w);
            *(uint2*)&Wbf[i] = p;
        }
        {
            float4 v = *(const float4*)&Wout[i];
            uint2 p; p.x = pk2(v.x, v.y); p.y = pk2(v.z, v.w);
            *(uint2*)&WoutBf[i] = p;
        }
    }
}

// ---------- layers: 768 blocks @ 3/CU (all resident), 4 waves, tile 64s x 256d ----------
// bmm BK=64 x8: bufA dbuf (cross-wave, 2-barrier counted-vmcnt); bufB wave-PRIVATE
// single 8KB slice (no barrier, restaged after own lgkm drain). mm2: Ps LDS +
// wave-private Wst 4KB slice, barrier-free K-loop.
template<int L>
__global__ __launch_bounds__(256, 3) void layers_kernel(
    const unsigned short* __restrict__ adjBf,  // [3][B][S][S] (diag+1)
    const unsigned short* __restrict__ XbfT,   // [B][D][S]        (L==0 input)
    unsigned short* __restrict__ yTh,          // [3][B][D][S]     (L==0 out / L==1 in)
    const unsigned short* __restrict__ Wbf,    // [6][D][D]
    const float* __restrict__ bvec,            // [6][D]
    const float* __restrict__ dInv,            // [3][B][S]
    unsigned short* __restrict__ yAll)         // [6][B][S][D]
{
    __shared__ __align__(16) char smem[50176];
    // bmm: bufA dbuf [0,16384) (2 x 64rows x 128B); bufB slice w: [16384 + w*8192, +8192)
    // mm2 overlay: Ps [0,33792) stride 264; Wst slice w: [33792 + w*4096, +4096)

    const int tid = threadIdx.x;
    const int w   = tid >> 6;
    const int l   = tid & 63;
    const int lm  = l & 15;
    const int g   = l >> 4;

    int flat = blockIdx.x;
    flat = (flat & 7) * 96 + (flat >> 3);      // XCD-chunked (768 = 8*96, bijective)
    const int h  = flat >> 8;
    const int rem = flat & 255;
    const int b  = rem >> 3;
    const int s0 = (rem & 7) * 64;

    const unsigned short* adjB = adjBf + (((int64_t)h * B_ + b) * S_ + s0) * S_;
    const unsigned short* xTB  = (L == 0) ? (XbfT + (int64_t)b * D_ * S_)
                                          : (yTh + ((int64_t)h * B_ + b) * D_ * S_);
    const unsigned short* Wl   = Wbf + (int64_t)(h * 2 + L) * D_ * D_;
    const float* bl            = bvec + (h * 2 + L) * D_;
    const float* dInvB         = dInv + ((int64_t)h * B_ + b) * S_ + s0;
    unsigned short* y          = yAll + (int64_t)(h * 2 + L) * XSZ + ((int64_t)(b * S_ + s0)) * D_;

    const int srow8  = l >> 3;                   // row-in-8
    const int schunk = ((l & 7) ^ (l >> 3)) * 8; // pre-swizzled source col (shorts)

    f32x4 acc[4][4];
#pragma unroll
    for (int i = 0; i < 4; i++)
#pragma unroll
        for (int j = 0; j < 4; j++) acc[i][j] = (f32x4){0.f, 0.f, 0.f, 0.f};

    auto stageA = [&](int t0, int cur) {         // 2 gl_lds per wave (cross-wave tile)
        char* bA = smem + cur * 8192;
        gl_lds16(&adjB[(w * 16 + srow8) * S_ + t0 + schunk], bA + w * 2048);
        gl_lds16(&adjB[(w * 16 + 8 + srow8) * S_ + t0 + schunk], bA + w * 2048 + 1024);
    };
    auto stageB = [&](int t0) {                  // 8 gl_lds into OWN slice
        char* bB = smem + 16384 + w * 8192;
#pragma unroll
        for (int j = 0; j < 8; j++)
            gl_lds16(&xTB[(int64_t)(w * 64 + j * 8 + srow8) * S_ + t0 + schunk],
                     bB + j * 1024);
    };
    auto compute = [&](int cur) {
        const char* bA = smem + cur * 8192;
        const char* bB = smem + 16384 + w * 8192;
        __builtin_amdgcn_s_setprio(1);
#pragma unroll
        for (int h2 = 0; h2 < 2; h2++) {
            const int co = ((h2 * 4 + g) ^ (lm & 7)) * 16;
            bf16x8 aF[4];
#pragma unroll
            for (int mi = 0; mi < 4; mi++)
                aF[mi] = *(const bf16x8*)(bA + (mi * 16 + lm) * 128 + co);
#pragma unroll
            for (int ni = 0; ni < 4; ni++) {
                bf16x8 bF = *(const bf16x8*)(bB + (ni * 16 + lm) * 128 + co);
#pragma unroll
                for (int mi = 0; mi < 4; mi++)
                    acc[mi][ni] = MF(aF[mi], bF, acc[mi][ni]);
            }
        }
        __builtin_amdgcn_s_setprio(0);
    };

    // ---- bmm: P = (A+I)x, 8 steps of BK=64 ----
    stageB(0);
    stageA(0, 0);
    for (int t = 0; t < 8; t++) {
        const int cur = t & 1;
        if (t < 7) { stageA((t + 1) * 64, cur ^ 1); WAITVM(2); }  // drains A(t)+B(t)
        else       { WAITVM(0); }
        SCHEDB(); BAR(); SCHEDB();
        compute(cur);
        SCHEDB(); WAITLG(); SCHEDB();            // own ds_reads of B slice retired
        if (t < 7) stageB((t + 1) * 64);         // restage own slice (no barrier needed)
        BAR();                                   // protects bufA[cur] for next stageA
    }

    // ---- P -> Ps (bf16, stride 264) ----
    unsigned short* Ps = (unsigned short*)smem;
#pragma unroll
    for (int mi = 0; mi < 4; mi++)
#pragma unroll
        for (int ni = 0; ni < 4; ni++) {
            const int col = w * 64 + ni * 16 + lm;
#pragma unroll
            for (int r = 0; r < 4; r++)
                Ps[(mi * 16 + g * 4 + r) * 264 + col] = f2bf(acc[mi][ni][r]);
        }

    const int sr16 = l >> 2;
    const int sc4  = ((l & 3) ^ ((l >> 3) & 3)) * 8;
    auto stageW = [&](int kc) {                  // 4 gl_lds into OWN slice
        char* bW = smem + 33792 + w * 4096;
#pragma unroll
        for (int j = 0; j < 4; j++)
            gl_lds16(&Wl[(w * 64 + j * 16 + sr16) * D_ + kc * 32 + sc4],
                     bW + j * 1024);
    };
    stageW(0);
    __syncthreads();

    // ---- mm2: Q = P @ W^T, 8 steps of BK=32, barrier-free (W wave-private) ----
    f32x4 acc2[4][4];
#pragma unroll
    for (int i = 0; i < 4; i++)
#pragma unroll
        for (int j = 0; j < 4; j++) acc2[i][j] = (f32x4){0.f, 0.f, 0.f, 0.f};

    for (int kc = 0; kc < 8; kc++) {
        WAITVM(0);                               // own W(kc) landed
        SCHEDB();
        {
            const char* bW = smem + 33792 + w * 4096;
            const int co2 = (g ^ ((lm >> 1) & 3)) << 4;
            bf16x8 aF[4];
#pragma unroll
            for (int mi = 0; mi < 4; mi++)
                aF[mi] = *(const bf16x8*)&Ps[(mi * 16 + lm) * 264 + kc * 32 + g * 8];
            __builtin_amdgcn_s_setprio(1);
#pragma unroll
            for (int ni = 0; ni < 4; ni++) {
                bf16x8 bF = *(const bf16x8*)(bW + (ni * 16 + lm) * 64 + co2);
#pragma unroll
                for (int mi = 0; mi < 4; mi++)
                    acc2[mi][ni] = MF(aF[mi], bF, acc2[mi][ni]);
            }
            __builtin_amdgcn_s_setprio(0);
        }
        SCHEDB(); WAITLG(); SCHEDB();            // own Wst reads retired
        if (kc < 7) stageW(kc + 1);
    }
    __syncthreads();   // all Ps reads retired before epilogue overwrite

    // ---- epilogue: y = relu((Q + 2b) * dInv) ----
    float dv[4][4];
#pragma unroll
    for (int mi = 0; mi < 4; mi++)
#pragma unroll
        for (int r = 0; r < 4; r++)
            dv[mi][r] = dInvB[mi * 16 + g * 4 + r];

#pragma unroll
    for (int ni = 0; ni < 4; ni++) {
        const int col = w * 64 + ni * 16 + lm;
        const float bv = 2.0f * bl[col];
#pragma unroll
        for (int mi = 0; mi < 4; mi++)
#pragma unroll
            for (int r = 0; r < 4; r++) {
                float v = (acc2[mi][ni][r] + bv) * dv[mi][r];
                v = v > 0.f ? v : 0.f;
                Ps[(mi * 16 + g * 4 + r) * 264 + col] = f2bf(v);
            }
    }
    __syncthreads();

    // coalesced y store: 64 rows x 512B, 128B/thread
    {
        const int rr = tid >> 2, seg = (tid & 3) * 64;
        const uint4* srcp = (const uint4*)&Ps[rr * 264 + seg];
        uint4* dst = (uint4*)&y[rr * D_ + seg];
#pragma unroll
        for (int q = 0; q < 8; q++) dst[q] = srcp[q];
    }
    if (L == 0) {  // transposed yT for next layer's bmm
        unsigned short* yT = yTh + ((int64_t)h * B_ + b) * D_ * S_;
        const int e = tid;
        unsigned short tmp[64];
#pragma unroll
        for (int s = 0; s < 64; s++) tmp[s] = Ps[s * 264 + e];
        uint4* dst = (uint4*)&yT[(int64_t)e * S_ + s0];
#pragma unroll
        for (int q = 0; q < 8; q++) dst[q] = ((uint4*)tmp)[q];
    }
}

// ---------- final: 256 blocks, tile 64s x 256e, K=1536 (24 steps of 64) ----------
__global__ __launch_bounds__(256, 2) void final_kernel(
    const unsigned short* __restrict__ yAll,
    const unsigned short* __restrict__ WoutBf,  // [256][1536]
    const float* __restrict__ gcn,
    const float* __restrict__ bout,
    float* __restrict__ out)
{
    __shared__ __align__(16) char smem[81920];

    const int tid = threadIdx.x;
    const int w   = tid >> 6;
    const int l   = tid & 63;
    const int lm  = l & 15;
    const int g   = l >> 4;

    int flat = blockIdx.x;
    flat = (flat & 7) * 32 + (flat >> 3);       // 256 = 8*32, bijective
    const int b  = flat >> 3;
    const int s0 = (flat & 7) * 64;

    const int srow8  = l >> 3;
    const int schunk = ((l & 7) ^ (l >> 3)) * 8;
    const unsigned short* yBase = yAll + (int64_t)(b * S_ + s0) * D_;

    auto stage = [&](int kc, int cur) {          // 10 gl_lds per wave
        char* bA = smem + cur * 8192;
        char* bB = smem + 16384 + cur * 32768;
        const int hl = kc >> 2;
        const int e0 = (kc & 3) * 64;
        gl_lds16(&yBase[(int64_t)hl * XSZ + (w * 16 + srow8) * D_ + e0 + schunk],
                 bA + w * 2048);
        gl_lds16(&yBase[(int64_t)hl * XSZ + (w * 16 + 8 + srow8) * D_ + e0 + schunk],
                 bA + w * 2048 + 1024);
#pragma unroll
        for (int j = 0; j < 8; j++)
            gl_lds16(&WoutBf[(w * 64 + j * 8 + srow8) * 1536 + kc * 64 + schunk],
                     bB + w * 8192 + j * 1024);
    };

    f32x4 acc[4][4];
#pragma unroll
    for (int i = 0; i < 4; i++)
#pragma unroll
        for (int j = 0; j < 4; j++) acc[i][j] = (f32x4){0.f, 0.f, 0.f, 0.f};

    stage(0, 0);
    for (int t = 0; t < 24; t++) {
        const int cur = t & 1;
        if (t < 23) { stage(t + 1, cur ^ 1); WAITVM(10); }
        else        { WAITVM(0); }
        SCHEDB(); BAR(); SCHEDB();
        {
            const char* bA = smem + cur * 8192;
            const char* bB = smem + 16384 + cur * 32768;
            __builtin_amdgcn_s_setprio(1);
#pragma unroll
            for (int h2 = 0; h2 < 2; h2++) {
                const int co = (((h2 * 4 + g) ^ (lm & 7)) << 4);
                bf16x8 aF[4];
#pragma unroll
                for (int mi = 0; mi < 4; mi++)
                    aF[mi] = *(const bf16x8*)(bA + (mi * 16 + lm) * 128 + co);
#pragma unroll
                for (int ni = 0; ni < 4; ni++) {
                    bf16x8 bF = *(const bf16x8*)(bB + (w * 64 + ni * 16 + lm) * 128 + co);
#pragma unroll
                    for (int mi = 0; mi < 4; mi++)
                        acc[mi][ni] = MF(aF[mi], bF, acc[mi][ni]);
                }
            }
            __builtin_amdgcn_s_setprio(0);
        }
        SCHEDB(); BAR();
    }

#pragma unroll
    for (int ni = 0; ni < 4; ni++) {
        const int e = w * 64 + ni * 16 + lm;
        const float bo = bout[e];
#pragma unroll
        for (int mi = 0; mi < 4; mi++)
#pragma unroll
            for (int r = 0; r < 4; r++) {
                const int row = mi * 16 + g * 4 + r;
                const int64_t idx = ((int64_t)(b * S_ + s0 + row)) * D_ + e;
                out[idx] = acc[mi][ni][r] + gcn[idx] + bo;
            }
    }
}

extern "C" void kernel_launch(void* const* d_in, const int* in_sizes, int n_in,
                              void* d_out, int out_size, void* d_ws, size_t ws_size,
                              hipStream_t stream) {
    const float* adj  = (const float*)d_in[0];
    const float* gcn  = (const float*)d_in[1];
    const float* W    = (const float*)d_in[4];
    const float* bvec = (const float*)d_in[5];
    const float* Wout = (const float*)d_in[6];
    const float* bout = (const float*)d_in[7];
    float* out = (float*)d_out;

    const int64_t ADJ_N = (int64_t)3 * B_ * S_ * S_;
    unsigned short* adjBf  = (unsigned short*)d_ws;
    unsigned short* XbfT   = adjBf + ADJ_N;
    unsigned short* yAll   = XbfT + XSZ;        // 6 slices [B][S][D]
    unsigned short* yTh    = yAll + 6 * XSZ;    // 3 slices [B][D][S]
    unsigned short* Wbf    = yTh + 3 * XSZ;
    unsigned short* WoutBf = Wbf + 6 * D_ * D_;
    float* dInv            = (float*)(WoutBf + 6 * D_ * D_);  // [3][B][S]

    prep_kernel<<<13696, 256, 0, stream>>>(adj, gcn, W, Wout,
                                           adjBf, dInv, XbfT, Wbf, WoutBf);
    layers_kernel<0><<<768, 256, 0, stream>>>(adjBf, XbfT, yTh, Wbf, bvec, dInv, yAll);
    layers_kernel<1><<<768, 256, 0, stream>>>(adjBf, XbfT, yTh, Wbf, bvec, dInv, yAll);
    final_kernel<<<256, 256, 0, stream>>>(yAll, WoutBf, gcn, bout, out);
}

// Round 10
// 126.933 us; speedup vs baseline: 1.0913x; 1.0152x over previous
//
#include <hip/hip_runtime.h>
#include <stdint.h>

#define S_ 512
#define B_ 32
#define D_ 256
#define XSZ ((int64_t)B_ * S_ * D_)

typedef __attribute__((ext_vector_type(8))) short bf16x8;
typedef __attribute__((ext_vector_type(4))) float f32x4;

#define WAITVM(n) asm volatile("s_waitcnt vmcnt(" #n ")" ::: "memory")
#define WAITLG() asm volatile("s_waitcnt lgkmcnt(0)" ::: "memory")
#define SCHEDB() __builtin_amdgcn_sched_barrier(0)
#define BAR() __builtin_amdgcn_s_barrier()

__device__ __forceinline__ unsigned short f2bf(float f) {
    union { float f; uint32_t u; } v; v.f = f;
    uint32_t r = v.u + 0x7FFFu + ((v.u >> 16) & 1u);
    return (unsigned short)(r >> 16);
}
__device__ __forceinline__ uint32_t pk2(float a, float b) {
    return (uint32_t)f2bf(a) | ((uint32_t)f2bf(b) << 16);
}

__device__ __forceinline__ void gl_lds16(const unsigned short* g, void* lds_base) {
    __builtin_amdgcn_global_load_lds(
        (const __attribute__((address_space(1))) unsigned int*)g,
        (__attribute__((address_space(3))) unsigned int*)lds_base, 16, 0, 0);
}

__device__ __forceinline__ f32x4 MF(bf16x8 a, bf16x8 b, f32x4 c) {
    return __builtin_amdgcn_mfma_f32_16x16x32_bf16(a, b, c, 0, 0, 0);
}

// ---------- fused prep: [0,12288) adj  [12288,13312) xT  [13312,13696) W ----------
__global__ __launch_bounds__(256) void prep_kernel(
    const float* __restrict__ adj, const float* __restrict__ gcn,
    const float* __restrict__ W, const float* __restrict__ Wout,
    unsigned short* __restrict__ adjBf, float* __restrict__ dInv,
    unsigned short* __restrict__ XbfT,
    unsigned short* __restrict__ Wbf, unsigned short* __restrict__ WoutBf)
{
    __shared__ unsigned short T[64 * 65];
    const int bx = blockIdx.x;
    const int tid = threadIdx.x;

    if (bx < 12288) {  // ---- adj: bf16 + I, dInv ----
        const int flat = bx * 4 + (tid >> 6);
        const int lane = tid & 63;
        const float* src = adj + (int64_t)flat * S_ + lane * 8;
        float4 v0 = ((const float4*)src)[0];
        float4 v1 = ((const float4*)src)[1];
        float sum = v0.x + v0.y + v0.z + v0.w + v1.x + v1.y + v1.z + v1.w;
#pragma unroll
        for (int o = 1; o < 64; o <<= 1) sum += __shfl_xor(sum, o);
        const int s = flat & (S_ - 1);
        const int c0 = lane * 8;
        float e0 = v0.x + ((s == c0 + 0) ? 1.f : 0.f);
        float e1 = v0.y + ((s == c0 + 1) ? 1.f : 0.f);
        float e2 = v0.z + ((s == c0 + 2) ? 1.f : 0.f);
        float e3 = v0.w + ((s == c0 + 3) ? 1.f : 0.f);
        float e4 = v1.x + ((s == c0 + 4) ? 1.f : 0.f);
        float e5 = v1.y + ((s == c0 + 5) ? 1.f : 0.f);
        float e6 = v1.z + ((s == c0 + 6) ? 1.f : 0.f);
        float e7 = v1.w + ((s == c0 + 7) ? 1.f : 0.f);
        uint4 p;
        p.x = pk2(e0, e1); p.y = pk2(e2, e3);
        p.z = pk2(e4, e5); p.w = pk2(e6, e7);
        *(uint4*)&adjBf[(int64_t)flat * S_ + c0] = p;
        if (lane == 0) dInv[flat] = 1.0f / (sum + 1.0f);
    } else if (bx < 13312) {  // ---- gcn -> XbfT (transpose) ----
        const int idx = bx - 12288;
        const int s0 = (idx & 7) * 64, d0 = ((idx >> 3) & 3) * 64, b = idx >> 5;
        const int r = tid >> 2, seg = tid & 3;
        const float* src = gcn + ((int64_t)(b * S_ + s0 + r)) * D_ + d0 + seg * 16;
#pragma unroll
        for (int q = 0; q < 4; q++) {
            float4 v = ((const float4*)src)[q];
            unsigned short* t = &T[r * 65 + seg * 16 + q * 4];
            t[0] = f2bf(v.x); t[1] = f2bf(v.y); t[2] = f2bf(v.z); t[3] = f2bf(v.w);
        }
        __syncthreads();
        unsigned short tmp[16];
#pragma unroll
        for (int j = 0; j < 16; j++) tmp[j] = T[(seg * 16 + j) * 65 + r];
        unsigned short* dst = &XbfT[((int64_t)(b * D_ + d0 + r)) * S_ + s0 + seg * 16];
        ((uint4*)dst)[0] = ((uint4*)tmp)[0];
        ((uint4*)dst)[1] = ((uint4*)tmp)[1];
    } else {  // ---- W, Wout -> bf16 ----
        const int i = ((bx - 13312) * 256 + tid) * 4;
        {
            float4 v = *(const float4*)&W[i];
            uint2 p; p.x = pk2(v.x, v.y); p.y = pk2(v.z, v.w);
            *(uint2*)&Wbf[i] = p;
        }
        {
            float4 v = *(const float4*)&Wout[i];
            uint2 p; p.x = pk2(v.x, v.y); p.y = pk2(v.z, v.w);
            *(uint2*)&WoutBf[i] = p;
        }
    }
}

// ---------- layers: 768 blocks @ 3/CU, 4 waves, tile 64s x 256d ----------
// bmm BK=64 x8: bufA dbuf cross-wave; bufB wave-private, ISSUE-EARLY restage
// (read frags->regs, lgkm drain, restage, then MFMA cluster covers the latency).
template<int L>
__global__ __launch_bounds__(256, 3) void layers_kernel(
    const unsigned short* __restrict__ adjBf,  // [3][B][S][S] (diag+1)
    const unsigned short* __restrict__ XbfT,   // [B][D][S]        (L==0 input)
    unsigned short* __restrict__ yTh,          // [3][B][D][S]     (L==0 out / L==1 in)
    const unsigned short* __restrict__ Wbf,    // [6][D][D]
    const float* __restrict__ bvec,            // [6][D]
    const float* __restrict__ dInv,            // [3][B][S]
    unsigned short* __restrict__ yAll)         // [6][B][S][D]
{
    __shared__ __align__(16) char smem[50176];
    // bufA dbuf [0,16384); bufB slice w: [16384 + w*8192, +8192)
    // mm2 overlay: Ps [0,33792) stride 264; Wst slice w: [33792 + w*4096, +4096)

    const int tid = threadIdx.x;
    const int w   = tid >> 6;
    const int l   = tid & 63;
    const int lm  = l & 15;
    const int g   = l >> 4;

    int flat = blockIdx.x;
    flat = (flat & 7) * 96 + (flat >> 3);      // XCD-chunked (768 = 8*96, bijective)
    const int h  = flat >> 8;
    const int rem = flat & 255;
    const int b  = rem >> 3;
    const int s0 = (rem & 7) * 64;

    const unsigned short* adjB = adjBf + (((int64_t)h * B_ + b) * S_ + s0) * S_;
    const unsigned short* xTB  = (L == 0) ? (XbfT + (int64_t)b * D_ * S_)
                                          : (yTh + ((int64_t)h * B_ + b) * D_ * S_);
    const unsigned short* Wl   = Wbf + (int64_t)(h * 2 + L) * D_ * D_;
    const float* bl            = bvec + (h * 2 + L) * D_;
    const float* dInvB         = dInv + ((int64_t)h * B_ + b) * S_ + s0;
    unsigned short* y          = yAll + (int64_t)(h * 2 + L) * XSZ + ((int64_t)(b * S_ + s0)) * D_;

    const int srow8  = l >> 3;                   // row-in-8
    const int schunk = ((l & 7) ^ (l >> 3)) * 8; // pre-swizzled source col (shorts)

    f32x4 acc[4][4];
#pragma unroll
    for (int i = 0; i < 4; i++)
#pragma unroll
        for (int j = 0; j < 4; j++) acc[i][j] = (f32x4){0.f, 0.f, 0.f, 0.f};

    auto stageA = [&](int t0, int cur) {         // 2 gl_lds per wave (cross-wave tile)
        char* bA = smem + cur * 8192;
        gl_lds16(&adjB[(w * 16 + srow8) * S_ + t0 + schunk], bA + w * 2048);
        gl_lds16(&adjB[(w * 16 + 8 + srow8) * S_ + t0 + schunk], bA + w * 2048 + 1024);
    };
    auto stageB = [&](int t0) {                  // 8 gl_lds into OWN slice
        char* bB = smem + 16384 + w * 8192;
#pragma unroll
        for (int j = 0; j < 8; j++)
            gl_lds16(&xTB[(int64_t)(w * 64 + j * 8 + srow8) * S_ + t0 + schunk],
                     bB + j * 1024);
    };

    // ---- bmm: P = (A+I)x, 8 steps of BK=64, issue-early B restage ----
    stageA(0, 0);
    stageB(0);
    for (int t = 0; t < 8; t++) {
        const int cur = t & 1;
        if (t < 7) { stageA((t + 1) * 64, cur ^ 1); WAITVM(2); }  // drains A(t)+B(t)
        else       { WAITVM(0); }
        SCHEDB(); BAR(); SCHEDB();
        {
            const char* bA = smem + cur * 8192;
            const char* bB = smem + 16384 + w * 8192;
            // read ALL B frags (both halves) to regs
            bf16x8 bF2[2][4];
#pragma unroll
            for (int h2 = 0; h2 < 2; h2++) {
                const int co = ((h2 * 4 + g) ^ (lm & 7)) * 16;
#pragma unroll
                for (int ni = 0; ni < 4; ni++)
                    bF2[h2][ni] = *(const bf16x8*)(bB + (ni * 16 + lm) * 128 + co);
            }
            WAITLG(); SCHEDB();
            if (t < 7) stageB((t + 1) * 64);     // issue-early: latency under MFMAs
            SCHEDB();
            __builtin_amdgcn_s_setprio(1);
#pragma unroll
            for (int h2 = 0; h2 < 2; h2++) {
                const int co = ((h2 * 4 + g) ^ (lm & 7)) * 16;
                bf16x8 aF[4];
#pragma unroll
                for (int mi = 0; mi < 4; mi++)
                    aF[mi] = *(const bf16x8*)(bA + (mi * 16 + lm) * 128 + co);
#pragma unroll
                for (int ni = 0; ni < 4; ni++)
#pragma unroll
                    for (int mi = 0; mi < 4; mi++)
                        acc[mi][ni] = MF(aF[mi], bF2[h2][ni], acc[mi][ni]);
            }
            __builtin_amdgcn_s_setprio(0);
        }
        SCHEDB(); BAR();                         // protects bufA[cur] for next stageA
    }

    // ---- P -> Ps (bf16, stride 264) ----
    unsigned short* Ps = (unsigned short*)smem;
#pragma unroll
    for (int mi = 0; mi < 4; mi++)
#pragma unroll
        for (int ni = 0; ni < 4; ni++) {
            const int col = w * 64 + ni * 16 + lm;
#pragma unroll
            for (int r = 0; r < 4; r++)
                Ps[(mi * 16 + g * 4 + r) * 264 + col] = f2bf(acc[mi][ni][r]);
        }

    const int sr16 = l >> 2;
    const int sc4  = ((l & 3) ^ ((l >> 3) & 3)) * 8;
    auto stageW = [&](int kc) {                  // 4 gl_lds into OWN slice
        char* bW = smem + 33792 + w * 4096;
#pragma unroll
        for (int j = 0; j < 4; j++)
            gl_lds16(&Wl[(w * 64 + j * 16 + sr16) * D_ + kc * 32 + sc4],
                     bW + j * 1024);
    };
    stageW(0);
    __syncthreads();

    // ---- mm2: Q = P @ W^T, 8 steps of BK=32, barrier-free, issue-early W ----
    f32x4 acc2[4][4];
#pragma unroll
    for (int i = 0; i < 4; i++)
#pragma unroll
        for (int j = 0; j < 4; j++) acc2[i][j] = (f32x4){0.f, 0.f, 0.f, 0.f};

    for (int kc = 0; kc < 8; kc++) {
        WAITVM(0);                               // own W(kc) landed
        SCHEDB();
        {
            const char* bW = smem + 33792 + w * 4096;
            const int co2 = (g ^ ((lm >> 1) & 3)) << 4;
            bf16x8 bF[4];
#pragma unroll
            for (int ni = 0; ni < 4; ni++)
                bF[ni] = *(const bf16x8*)(bW + (ni * 16 + lm) * 64 + co2);
            WAITLG(); SCHEDB();
            if (kc < 7) stageW(kc + 1);          // issue-early
            SCHEDB();
            bf16x8 aF[4];
#pragma unroll
            for (int mi = 0; mi < 4; mi++)
                aF[mi] = *(const bf16x8*)&Ps[(mi * 16 + lm) * 264 + kc * 32 + g * 8];
            __builtin_amdgcn_s_setprio(1);
#pragma unroll
            for (int ni = 0; ni < 4; ni++)
#pragma unroll
                for (int mi = 0; mi < 4; mi++)
                    acc2[mi][ni] = MF(aF[mi], bF[ni], acc2[mi][ni]);
            __builtin_amdgcn_s_setprio(0);
        }
    }
    __syncthreads();   // all Ps reads retired before epilogue overwrite

    // ---- epilogue: y = relu((Q + 2b) * dInv) ----
    float dv[4][4];
#pragma unroll
    for (int mi = 0; mi < 4; mi++)
#pragma unroll
        for (int r = 0; r < 4; r++)
            dv[mi][r] = dInvB[mi * 16 + g * 4 + r];

#pragma unroll
    for (int ni = 0; ni < 4; ni++) {
        const int col = w * 64 + ni * 16 + lm;
        const float bv = 2.0f * bl[col];
#pragma unroll
        for (int mi = 0; mi < 4; mi++)
#pragma unroll
            for (int r = 0; r < 4; r++) {
                float v = (acc2[mi][ni][r] + bv) * dv[mi][r];
                v = v > 0.f ? v : 0.f;
                Ps[(mi * 16 + g * 4 + r) * 264 + col] = f2bf(v);
            }
    }
    __syncthreads();

    // coalesced y store: 64 rows x 512B, 128B/thread
    {
        const int rr = tid >> 2, seg = (tid & 3) * 64;
        const uint4* srcp = (const uint4*)&Ps[rr * 264 + seg];
        uint4* dst = (uint4*)&y[rr * D_ + seg];
#pragma unroll
        for (int q = 0; q < 8; q++) dst[q] = srcp[q];
    }
    if (L == 0) {  // transposed yT for next layer's bmm
        unsigned short* yT = yTh + ((int64_t)h * B_ + b) * D_ * S_;
        const int e = tid;
        unsigned short tmp[64];
#pragma unroll
        for (int s = 0; s < 64; s++) tmp[s] = Ps[s * 264 + e];
        uint4* dst = (uint4*)&yT[(int64_t)e * S_ + s0];
#pragma unroll
        for (int q = 0; q < 8; q++) dst[q] = ((uint4*)tmp)[q];
    }
}

// ---------- final: 512 blocks @ 4/CU (all resident), 32s x 256e, BK=64 x24 ----------
// bufA (y rows) dbuf cross-wave; bufB (Wout rows, wave-private) issue-early restage.
__global__ __launch_bounds__(256, 4) void final_kernel(
    const unsigned short* __restrict__ yAll,
    const unsigned short* __restrict__ WoutBf,  // [256][1536]
    const float* __restrict__ gcn,
    const float* __restrict__ bout,
    float* __restrict__ out)
{
    __shared__ __align__(16) char smem[40960];
    // bufA dbuf [0,8192) (2 x 32rows x 128B); bufB slice w: [8192 + w*8192, +8192)

    const int tid = threadIdx.x;
    const int w   = tid >> 6;
    const int l   = tid & 63;
    const int lm  = l & 15;
    const int g   = l >> 4;

    int flat = blockIdx.x;
    flat = (flat & 7) * 64 + (flat >> 3);    // 512 = 8*64, bijective
    const int b  = flat >> 4;
    const int s0 = (flat & 15) * 32;

    const int srow8  = l >> 3;
    const int schunk = ((l & 7) ^ (l >> 3)) * 8;
    const unsigned short* yBase = yAll + (int64_t)(b * S_ + s0) * D_;

    auto stageA = [&](int kc, int cur) {      // 1 gl_lds per wave (cross-wave 32-row tile)
        char* bA = smem + cur * 4096;
        const int hl = kc >> 2;
        const int e0 = (kc & 3) * 64;
        gl_lds16(&yBase[(int64_t)hl * XSZ + (w * 8 + srow8) * D_ + e0 + schunk],
                 bA + w * 1024);
    };
    auto stageB = [&](int kc) {               // 8 gl_lds into OWN slice (Wout rows w*64..)
        char* bB = smem + 8192 + w * 8192;
#pragma unroll
        for (int j = 0; j < 8; j++)
            gl_lds16(&WoutBf[(w * 64 + j * 8 + srow8) * 1536 + kc * 64 + schunk],
                     bB + j * 1024);
    };

    f32x4 acc[2][4];
#pragma unroll
    for (int i = 0; i < 2; i++)
#pragma unroll
        for (int j = 0; j < 4; j++) acc[i][j] = (f32x4){0.f, 0.f, 0.f, 0.f};

    stageA(0, 0);
    stageB(0);
    for (int t = 0; t < 24; t++) {
        const int cur = t & 1;
        if (t < 23) { stageA(t + 1, cur ^ 1); WAITVM(1); }  // drains A(t)+B(t)
        else        { WAITVM(0); }
        SCHEDB(); BAR(); SCHEDB();
        {
            const char* bA = smem + cur * 4096;
            const char* bB = smem + 8192 + w * 8192;
            bf16x8 bF2[2][4];
#pragma unroll
            for (int h2 = 0; h2 < 2; h2++) {
                const int co = (((h2 * 4 + g) ^ (lm & 7)) << 4);
#pragma unroll
                for (int ni = 0; ni < 4; ni++)
                    bF2[h2][ni] = *(const bf16x8*)(bB + (ni * 16 + lm) * 128 + co);
            }
            WAITLG(); SCHEDB();
            if (t < 23) stageB(t + 1);           // issue-early
            SCHEDB();
            __builtin_amdgcn_s_setprio(1);
#pragma unroll
            for (int h2 = 0; h2 < 2; h2++) {
                const int co = (((h2 * 4 + g) ^ (lm & 7)) << 4);
                bf16x8 a0 = *(const bf16x8*)(bA + lm * 128 + co);
                bf16x8 a1 = *(const bf16x8*)(bA + (16 + lm) * 128 + co);
#pragma unroll
                for (int ni = 0; ni < 4; ni++) {
                    acc[0][ni] = MF(a0, bF2[h2][ni], acc[0][ni]);
                    acc[1][ni] = MF(a1, bF2[h2][ni], acc[1][ni]);
                }
            }
            __builtin_amdgcn_s_setprio(0);
        }
        SCHEDB(); BAR();
    }

#pragma unroll
    for (int ni = 0; ni < 4; ni++) {
        const int e = w * 64 + ni * 16 + lm;
        const float bo = bout[e];
#pragma unroll
        for (int mi = 0; mi < 2; mi++)
#pragma unroll
            for (int r = 0; r < 4; r++) {
                const int row = mi * 16 + g * 4 + r;
                const int64_t idx = ((int64_t)(b * S_ + s0 + row)) * D_ + e;
                out[idx] = acc[mi][ni][r] + gcn[idx] + bo;
            }
    }
}

extern "C" void kernel_launch(void* const* d_in, const int* in_sizes, int n_in,
                              void* d_out, int out_size, void* d_ws, size_t ws_size,
                              hipStream_t stream) {
    const float* adj  = (const float*)d_in[0];
    const float* gcn  = (const float*)d_in[1];
    const float* W    = (const float*)d_in[4];
    const float* bvec = (const float*)d_in[5];
    const float* Wout = (const float*)d_in[6];
    const float* bout = (const float*)d_in[7];
    float* out = (float*)d_out;

    const int64_t ADJ_N = (int64_t)3 * B_ * S_ * S_;
    unsigned short* adjBf  = (unsigned short*)d_ws;
    unsigned short* XbfT   = adjBf + ADJ_N;
    unsigned short* yAll   = XbfT + XSZ;        // 6 slices [B][S][D]
    unsigned short* yTh    = yAll + 6 * XSZ;    // 3 slices [B][D][S]
    unsigned short* Wbf    = yTh + 3 * XSZ;
    unsigned short* WoutBf = Wbf + 6 * D_ * D_;
    float* dInv            = (float*)(WoutBf + 6 * D_ * D_);  // [3][B][S]

    prep_kernel<<<13696, 256, 0, stream>>>(adj, gcn, W, Wout,
                                           adjBf, dInv, XbfT, Wbf, WoutBf);
    layers_kernel<0><<<768, 256, 0, stream>>>(adjBf, XbfT, yTh, Wbf, bvec, dInv, yAll);
    layers_kernel<1><<<768, 256, 0, stream>>>(adjBf, XbfT, yTh, Wbf, bvec, dInv, yAll);
    final_kernel<<<512, 256, 0, stream>>>(yAll, WoutBf, gcn, bout, out);
}

// Round 11
// 121.627 us; speedup vs baseline: 1.1389x; 1.0436x over previous
//
#include <hip/hip_runtime.h>
#include <stdint.h>

#define S_ 512
#define B_ 32
#define D_ 256
#define XSZ ((int64_t)B_ * S_ * D_)

typedef __attribute__((ext_vector_type(8))) short bf16x8;
typedef __attribute__((ext_vector_type(4))) float f32x4;
typedef long long i64;

#define WAITVM(n) asm volatile("s_waitcnt vmcnt(" #n ")" ::: "memory")
#define WAITLG() asm volatile("s_waitcnt lgkmcnt(0)" ::: "memory")
#define SCHEDB() __builtin_amdgcn_sched_barrier(0)
#define BAR() __builtin_amdgcn_s_barrier()

__device__ __forceinline__ unsigned short f2bf(float f) {
    union { float f; uint32_t u; } v; v.f = f;
    uint32_t r = v.u + 0x7FFFu + ((v.u >> 16) & 1u);
    return (unsigned short)(r >> 16);
}
__device__ __forceinline__ float bf2f(unsigned short h) {
    union { uint32_t u; float f; } v; v.u = ((uint32_t)h) << 16;
    return v.f;
}
__device__ __forceinline__ uint32_t pk2(float a, float b) {
    return (uint32_t)f2bf(a) | ((uint32_t)f2bf(b) << 16);
}

// f32 -> fp8 e4m3fn, RNE. Inputs here are always |f| < 256 (no saturation path).
__device__ __forceinline__ uint32_t f2f8(float f) {
    union { float f; uint32_t u; } v; v.f = f;
    const uint32_t s = (v.u >> 24) & 0x80u;
    const int e = (int)((v.u >> 23) & 0xFF) - 127;
    const uint32_t m = v.u & 0x7FFFFFu;
    if (e >= -6) {                       // normal e4m3
        uint32_t mant = m >> 20;
        uint32_t rest = m & 0xFFFFFu;
        mant += (rest > 0x80000u) || (rest == 0x80000u && (mant & 1u));
        uint32_t exp = (uint32_t)(e + 7);
        if (mant == 8u) { mant = 0u; exp++; }
        return s | (exp << 3) | mant;
    }
    if (e < -10) return s;               // flush tiny to 0
    uint32_t full = 0x800000u | m;       // subnormal target: mant * 2^-9
    const int shift = 14 - e;            // e=-7 -> 21, e=-8 -> 22, e=-9 -> 23, e=-10 -> 24
    uint32_t mant = full >> shift;
    uint32_t rem = full & ((1u << shift) - 1u);
    uint32_t half = 1u << (shift - 1);
    mant += (rem > half) || (rem == half && (mant & 1u));
    if (mant >= 8u) return s | (1u << 3);
    return s | mant;
}
__device__ __forceinline__ uint32_t pk4f8(float a, float b, float c, float d) {
    return f2f8(a) | (f2f8(b) << 8) | (f2f8(c) << 16) | (f2f8(d) << 24);
}

__device__ __forceinline__ void gl_lds16(const void* g, void* lds_base) {
    __builtin_amdgcn_global_load_lds(
        (const __attribute__((address_space(1))) unsigned int*)g,
        (__attribute__((address_space(3))) unsigned int*)lds_base, 16, 0, 0);
}

__device__ __forceinline__ f32x4 MF(bf16x8 a, bf16x8 b, f32x4 c) {
    return __builtin_amdgcn_mfma_f32_16x16x32_bf16(a, b, c, 0, 0, 0);
}
__device__ __forceinline__ f32x4 MF8(i64 a, i64 b, f32x4 c) {
    return __builtin_amdgcn_mfma_f32_16x16x32_fp8_fp8(a, b, c, 0, 0, 0);
}

// ---------- fused prep: [0,12288) adj->fp8  [12288,13312) xT->fp8  [13312,13696) W->bf16 ----------
__global__ __launch_bounds__(256) void prep_kernel(
    const float* __restrict__ adj, const float* __restrict__ gcn,
    const float* __restrict__ W, const float* __restrict__ Wout,
    unsigned char* __restrict__ adjF8, float* __restrict__ dInv,
    unsigned char* __restrict__ Xf8T,
    unsigned short* __restrict__ Wbf, unsigned short* __restrict__ WoutBf)
{
    __shared__ unsigned short T[64 * 65];
    const int bx = blockIdx.x;
    const int tid = threadIdx.x;

    if (bx < 12288) {  // ---- adj: fp8 + I, dInv (rowsum from f32) ----
        const int flat = bx * 4 + (tid >> 6);
        const int lane = tid & 63;
        const float* src = adj + (int64_t)flat * S_ + lane * 8;
        float4 v0 = ((const float4*)src)[0];
        float4 v1 = ((const float4*)src)[1];
        float sum = v0.x + v0.y + v0.z + v0.w + v1.x + v1.y + v1.z + v1.w;
#pragma unroll
        for (int o = 1; o < 64; o <<= 1) sum += __shfl_xor(sum, o);
        const int s = flat & (S_ - 1);
        const int c0 = lane * 8;
        float e0 = v0.x + ((s == c0 + 0) ? 1.f : 0.f);
        float e1 = v0.y + ((s == c0 + 1) ? 1.f : 0.f);
        float e2 = v0.z + ((s == c0 + 2) ? 1.f : 0.f);
        float e3 = v0.w + ((s == c0 + 3) ? 1.f : 0.f);
        float e4 = v1.x + ((s == c0 + 4) ? 1.f : 0.f);
        float e5 = v1.y + ((s == c0 + 5) ? 1.f : 0.f);
        float e6 = v1.z + ((s == c0 + 6) ? 1.f : 0.f);
        float e7 = v1.w + ((s == c0 + 7) ? 1.f : 0.f);
        uint2 p;
        p.x = pk4f8(e0, e1, e2, e3);
        p.y = pk4f8(e4, e5, e6, e7);
        *(uint2*)&adjF8[(int64_t)flat * S_ + c0] = p;
        if (lane == 0) dInv[flat] = 1.0f / (sum + 1.0f);
    } else if (bx < 13312) {  // ---- gcn -> Xf8T (transpose, fp8) ----
        const int idx = bx - 12288;
        const int s0 = (idx & 7) * 64, d0 = ((idx >> 3) & 3) * 64, b = idx >> 5;
        const int r = tid >> 2, seg = tid & 3;
        const float* src = gcn + ((int64_t)(b * S_ + s0 + r)) * D_ + d0 + seg * 16;
#pragma unroll
        for (int q = 0; q < 4; q++) {
            float4 v = ((const float4*)src)[q];
            unsigned short* t = &T[r * 65 + seg * 16 + q * 4];
            t[0] = f2bf(v.x); t[1] = f2bf(v.y); t[2] = f2bf(v.z); t[3] = f2bf(v.w);
        }
        __syncthreads();
        uint32_t q8[4];
#pragma unroll
        for (int j = 0; j < 4; j++) {
            float a = bf2f(T[(seg * 16 + j * 4 + 0) * 65 + r]);
            float b2 = bf2f(T[(seg * 16 + j * 4 + 1) * 65 + r]);
            float c = bf2f(T[(seg * 16 + j * 4 + 2) * 65 + r]);
            float d = bf2f(T[(seg * 16 + j * 4 + 3) * 65 + r]);
            q8[j] = pk4f8(a, b2, c, d);
        }
        *(uint4*)&Xf8T[((int64_t)(b * D_ + d0 + r)) * S_ + s0 + seg * 16] = *(uint4*)q8;
    } else {  // ---- W, Wout -> bf16 ----
        const int i = ((bx - 13312) * 256 + tid) * 4;
        {
            float4 v = *(const float4*)&W[i];
            uint2 p; p.x = pk2(v.x, v.y); p.y = pk2(v.z, v.w);
            *(uint2*)&Wbf[i] = p;
        }
        {
            float4 v = *(const float4*)&Wout[i];
            uint2 p; p.x = pk2(v.x, v.y); p.y = pk2(v.z, v.w);
            *(uint2*)&WoutBf[i] = p;
        }
    }
}

// ---------- layers: 768 blocks @ 3/CU, 4 waves, tile 64s x 256d ----------
// bmm in FP8, BK=128 x4 steps (64 MFMA : 10 loads per wave per step).
// bufA dbuf cross-wave; bufB wave-private issue-early restage. mm2 bf16 as R10.
template<int L>
__global__ __launch_bounds__(256, 3) void layers_kernel(
    const unsigned char* __restrict__ adjF8,   // [3][B][S][S] fp8 (diag+1)
    const unsigned char* __restrict__ Xf8T,    // [B][D][S] fp8    (L==0 input)
    unsigned char* __restrict__ yT8,           // [3][B][D][S] fp8 (L==0 out / L==1 in)
    const unsigned short* __restrict__ Wbf,    // [6][D][D] bf16
    const float* __restrict__ bvec,            // [6][D]
    const float* __restrict__ dInv,            // [3][B][S]
    unsigned short* __restrict__ yAll)         // [6][B][S][D] bf16
{
    __shared__ __align__(16) char smem[50176];
    // bufA dbuf [0,16384) (2 x 64rows x 128B fp8 = BK=128)
    // bufB slice w: [16384 + w*8192, +8192) (64 rows x 128B)
    // mm2 overlay: Ps [0,33792) stride 264 bf16; Wst slice w: [33792 + w*4096, +4096)

    const int tid = threadIdx.x;
    const int w   = tid >> 6;
    const int l   = tid & 63;
    const int lm  = l & 15;
    const int g   = l >> 4;

    int flat = blockIdx.x;
    flat = (flat & 7) * 96 + (flat >> 3);      // XCD-chunked (768 = 8*96, bijective)
    const int h  = flat >> 8;
    const int rem = flat & 255;
    const int b  = rem >> 3;
    const int s0 = (rem & 7) * 64;

    const unsigned char* adjB = adjF8 + (((int64_t)h * B_ + b) * S_ + s0) * S_;
    const unsigned char* xTB  = (L == 0) ? (Xf8T + (int64_t)b * D_ * S_)
                                         : (yT8 + ((int64_t)h * B_ + b) * D_ * S_);
    const unsigned short* Wl  = Wbf + (int64_t)(h * 2 + L) * D_ * D_;
    const float* bl           = bvec + (h * 2 + L) * D_;
    const float* dInvB        = dInv + ((int64_t)h * B_ + b) * S_ + s0;
    unsigned short* y         = yAll + (int64_t)(h * 2 + L) * XSZ + ((int64_t)(b * S_ + s0)) * D_;

    const int srow8 = l >> 3;                    // row-in-8
    const int sch16 = ((l & 7) ^ (l >> 3)) * 16; // pre-swizzled source col (BYTES)

    f32x4 acc[4][4];
#pragma unroll
    for (int i = 0; i < 4; i++)
#pragma unroll
        for (int j = 0; j < 4; j++) acc[i][j] = (f32x4){0.f, 0.f, 0.f, 0.f};

    auto stageA = [&](int t0, int cur) {         // 2 gl_lds per wave
        char* bA = smem + cur * 8192;
        gl_lds16(&adjB[(w * 16 + srow8) * S_ + t0 + sch16], bA + w * 2048);
        gl_lds16(&adjB[(w * 16 + 8 + srow8) * S_ + t0 + sch16], bA + w * 2048 + 1024);
    };
    auto stageB = [&](int t0) {                  // 8 gl_lds into OWN slice
        char* bB = smem + 16384 + w * 8192;
#pragma unroll
        for (int j = 0; j < 8; j++)
            gl_lds16(&xTB[(int64_t)(w * 64 + j * 8 + srow8) * S_ + t0 + sch16],
                     bB + j * 1024);
    };

    // ---- bmm (fp8): P = (A+I)x, 4 steps of BK=128, issue-early B restage ----
    stageA(0, 0);
    stageB(0);
    for (int t = 0; t < 4; t++) {
        const int cur = t & 1;
        if (t < 3) { stageA((t + 1) * 128, cur ^ 1); WAITVM(2); }  // drains A(t)+B(t)
        else       { WAITVM(0); }
        SCHEDB(); BAR(); SCHEDB();
        {
            const char* bA = smem + cur * 8192;
            const char* bB = smem + 16384 + w * 8192;
            // read ALL B frags (4 kk-slices) to regs
            i64 bF2[4][4];
#pragma unroll
            for (int kk = 0; kk < 4; kk++) {
                const int co8 = (((kk * 2 + (g >> 1)) ^ (lm & 7)) << 4) + ((g & 1) << 3);
#pragma unroll
                for (int ni = 0; ni < 4; ni++)
                    bF2[kk][ni] = *(const i64*)(bB + (ni * 16 + lm) * 128 + co8);
            }
            WAITLG(); SCHEDB();
            if (t < 3) stageB((t + 1) * 128);    // issue-early: latency under 64 MFMAs
            SCHEDB();
            __builtin_amdgcn_s_setprio(1);
#pragma unroll
            for (int kk = 0; kk < 4; kk++) {
                const int co8 = (((kk * 2 + (g >> 1)) ^ (lm & 7)) << 4) + ((g & 1) << 3);
                i64 aF[4];
#pragma unroll
                for (int mi = 0; mi < 4; mi++)
                    aF[mi] = *(const i64*)(bA + (mi * 16 + lm) * 128 + co8);
#pragma unroll
                for (int ni = 0; ni < 4; ni++)
#pragma unroll
                    for (int mi = 0; mi < 4; mi++)
                        acc[mi][ni] = MF8(aF[mi], bF2[kk][ni], acc[mi][ni]);
            }
            __builtin_amdgcn_s_setprio(0);
        }
        SCHEDB(); BAR();                         // protects bufA[cur] for next stageA
    }

    // ---- P -> Ps (bf16, stride 264) ----
    unsigned short* Ps = (unsigned short*)smem;
#pragma unroll
    for (int mi = 0; mi < 4; mi++)
#pragma unroll
        for (int ni = 0; ni < 4; ni++) {
            const int col = w * 64 + ni * 16 + lm;
#pragma unroll
            for (int r = 0; r < 4; r++)
                Ps[(mi * 16 + g * 4 + r) * 264 + col] = f2bf(acc[mi][ni][r]);
        }

    const int sr16 = l >> 2;
    const int sc4  = ((l & 3) ^ ((l >> 3) & 3)) * 8;
    auto stageW = [&](int kc) {                  // 4 gl_lds into OWN slice
        char* bW = smem + 33792 + w * 4096;
#pragma unroll
        for (int j = 0; j < 4; j++)
            gl_lds16(&Wl[(w * 64 + j * 16 + sr16) * D_ + kc * 32 + sc4],
                     bW + j * 1024);
    };
    stageW(0);
    __syncthreads();

    // ---- mm2: Q = P @ W^T, 8 steps of BK=32, barrier-free, issue-early W ----
    f32x4 acc2[4][4];
#pragma unroll
    for (int i = 0; i < 4; i++)
#pragma unroll
        for (int j = 0; j < 4; j++) acc2[i][j] = (f32x4){0.f, 0.f, 0.f, 0.f};

    for (int kc = 0; kc < 8; kc++) {
        WAITVM(0);                               // own W(kc) landed
        SCHEDB();
        {
            const char* bW = smem + 33792 + w * 4096;
            const int co2 = (g ^ ((lm >> 1) & 3)) << 4;
            bf16x8 bF[4];
#pragma unroll
            for (int ni = 0; ni < 4; ni++)
                bF[ni] = *(const bf16x8*)(bW + (ni * 16 + lm) * 64 + co2);
            WAITLG(); SCHEDB();
            if (kc < 7) stageW(kc + 1);          // issue-early
            SCHEDB();
            bf16x8 aF[4];
#pragma unroll
            for (int mi = 0; mi < 4; mi++)
                aF[mi] = *(const bf16x8*)&Ps[(mi * 16 + lm) * 264 + kc * 32 + g * 8];
            __builtin_amdgcn_s_setprio(1);
#pragma unroll
            for (int ni = 0; ni < 4; ni++)
#pragma unroll
                for (int mi = 0; mi < 4; mi++)
                    acc2[mi][ni] = MF(aF[mi], bF[ni], acc2[mi][ni]);
            __builtin_amdgcn_s_setprio(0);
        }
    }
    __syncthreads();   // all Ps reads retired before epilogue overwrite

    // ---- epilogue: y = relu((Q + 2b) * dInv) ----
    float dv[4][4];
#pragma unroll
    for (int mi = 0; mi < 4; mi++)
#pragma unroll
        for (int r = 0; r < 4; r++)
            dv[mi][r] = dInvB[mi * 16 + g * 4 + r];

#pragma unroll
    for (int ni = 0; ni < 4; ni++) {
        const int col = w * 64 + ni * 16 + lm;
        const float bv = 2.0f * bl[col];
#pragma unroll
        for (int mi = 0; mi < 4; mi++)
#pragma unroll
            for (int r = 0; r < 4; r++) {
                float v = (acc2[mi][ni][r] + bv) * dv[mi][r];
                v = v > 0.f ? v : 0.f;
                Ps[(mi * 16 + g * 4 + r) * 264 + col] = f2bf(v);
            }
    }
    __syncthreads();

    // coalesced y store (bf16, for final): 64 rows x 512B, 128B/thread
    {
        const int rr = tid >> 2, seg = (tid & 3) * 64;
        const uint4* srcp = (const uint4*)&Ps[rr * 264 + seg];
        uint4* dst = (uint4*)&y[rr * D_ + seg];
#pragma unroll
        for (int q = 0; q < 8; q++) dst[q] = srcp[q];
    }
    if (L == 0) {  // transposed fp8 yT for L1's bmm B-operand
        unsigned char* yT = yT8 + ((int64_t)h * B_ + b) * D_ * S_;
        const int e = tid;
        uint32_t tmp[16];
#pragma unroll
        for (int sq = 0; sq < 16; sq++) {
            float a = bf2f(Ps[(sq * 4 + 0) * 264 + e]);
            float b2 = bf2f(Ps[(sq * 4 + 1) * 264 + e]);
            float c = bf2f(Ps[(sq * 4 + 2) * 264 + e]);
            float d = bf2f(Ps[(sq * 4 + 3) * 264 + e]);
            tmp[sq] = pk4f8(a, b2, c, d);
        }
        uint4* dst = (uint4*)&yT[(int64_t)e * S_ + s0];
#pragma unroll
        for (int q = 0; q < 4; q++) dst[q] = ((uint4*)tmp)[q];
    }
}

// ---------- final: 512 blocks @ 4/CU, 32s x 256e, BK=64 x24 (bf16, as R10) ----------
__global__ __launch_bounds__(256, 4) void final_kernel(
    const unsigned short* __restrict__ yAll,
    const unsigned short* __restrict__ WoutBf,  // [256][1536]
    const float* __restrict__ gcn,
    const float* __restrict__ bout,
    float* __restrict__ out)
{
    __shared__ __align__(16) char smem[40960];

    const int tid = threadIdx.x;
    const int w   = tid >> 6;
    const int l   = tid & 63;
    const int lm  = l & 15;
    const int g   = l >> 4;

    int flat = blockIdx.x;
    flat = (flat & 7) * 64 + (flat >> 3);    // 512 = 8*64, bijective
    const int b  = flat >> 4;
    const int s0 = (flat & 15) * 32;

    const int srow8  = l >> 3;
    const int schunk = ((l & 7) ^ (l >> 3)) * 8;
    const unsigned short* yBase = yAll + (int64_t)(b * S_ + s0) * D_;

    auto stageA = [&](int kc, int cur) {      // 1 gl_lds per wave
        char* bA = smem + cur * 4096;
        const int hl = kc >> 2;
        const int e0 = (kc & 3) * 64;
        gl_lds16(&yBase[(int64_t)hl * XSZ + (w * 8 + srow8) * D_ + e0 + schunk],
                 bA + w * 1024);
    };
    auto stageB = [&](int kc) {               // 8 gl_lds into OWN slice
        char* bB = smem + 8192 + w * 8192;
#pragma unroll
        for (int j = 0; j < 8; j++)
            gl_lds16(&WoutBf[(w * 64 + j * 8 + srow8) * 1536 + kc * 64 + schunk],
                     bB + j * 1024);
    };

    f32x4 acc[2][4];
#pragma unroll
    for (int i = 0; i < 2; i++)
#pragma unroll
        for (int j = 0; j < 4; j++) acc[i][j] = (f32x4){0.f, 0.f, 0.f, 0.f};

    stageA(0, 0);
    stageB(0);
    for (int t = 0; t < 24; t++) {
        const int cur = t & 1;
        if (t < 23) { stageA(t + 1, cur ^ 1); WAITVM(1); }
        else        { WAITVM(0); }
        SCHEDB(); BAR(); SCHEDB();
        {
            const char* bA = smem + cur * 4096;
            const char* bB = smem + 8192 + w * 8192;
            bf16x8 bF2[2][4];
#pragma unroll
            for (int h2 = 0; h2 < 2; h2++) {
                const int co = (((h2 * 4 + g) ^ (lm & 7)) << 4);
#pragma unroll
                for (int ni = 0; ni < 4; ni++)
                    bF2[h2][ni] = *(const bf16x8*)(bB + (ni * 16 + lm) * 128 + co);
            }
            WAITLG(); SCHEDB();
            if (t < 23) stageB(t + 1);
            SCHEDB();
            __builtin_amdgcn_s_setprio(1);
#pragma unroll
            for (int h2 = 0; h2 < 2; h2++) {
                const int co = (((h2 * 4 + g) ^ (lm & 7)) << 4);
                bf16x8 a0 = *(const bf16x8*)(bA + lm * 128 + co);
                bf16x8 a1 = *(const bf16x8*)(bA + (16 + lm) * 128 + co);
#pragma unroll
                for (int ni = 0; ni < 4; ni++) {
                    acc[0][ni] = MF(a0, bF2[h2][ni], acc[0][ni]);
                    acc[1][ni] = MF(a1, bF2[h2][ni], acc[1][ni]);
                }
            }
            __builtin_amdgcn_s_setprio(0);
        }
        SCHEDB(); BAR();
    }

#pragma unroll
    for (int ni = 0; ni < 4; ni++) {
        const int e = w * 64 + ni * 16 + lm;
        const float bo = bout[e];
#pragma unroll
        for (int mi = 0; mi < 2; mi++)
#pragma unroll
            for (int r = 0; r < 4; r++) {
                const int row = mi * 16 + g * 4 + r;
                const int64_t idx = ((int64_t)(b * S_ + s0 + row)) * D_ + e;
                out[idx] = acc[mi][ni][r] + gcn[idx] + bo;
            }
    }
}

extern "C" void kernel_launch(void* const* d_in, const int* in_sizes, int n_in,
                              void* d_out, int out_size, void* d_ws, size_t ws_size,
                              hipStream_t stream) {
    const float* adj  = (const float*)d_in[0];
    const float* gcn  = (const float*)d_in[1];
    const float* W    = (const float*)d_in[4];
    const float* bvec = (const float*)d_in[5];
    const float* Wout = (const float*)d_in[6];
    const float* bout = (const float*)d_in[7];
    float* out = (float*)d_out;

    const int64_t ADJ_N = (int64_t)3 * B_ * S_ * S_;   // fp8 bytes
    unsigned char* adjF8  = (unsigned char*)d_ws;
    unsigned char* Xf8T   = adjF8 + ADJ_N;             // B*D*S bytes
    unsigned char* yT8    = Xf8T + XSZ;                // 3*B*D*S bytes
    unsigned short* yAll  = (unsigned short*)(yT8 + 3 * XSZ);   // 6 slices bf16
    unsigned short* Wbf   = yAll + 6 * XSZ;
    unsigned short* WoutBf= Wbf + 6 * D_ * D_;
    float* dInv           = (float*)(WoutBf + 6 * D_ * D_);     // [3][B][S]

    prep_kernel<<<13696, 256, 0, stream>>>(adj, gcn, W, Wout,
                                           adjF8, dInv, Xf8T, Wbf, WoutBf);
    layers_kernel<0><<<768, 256, 0, stream>>>(adjF8, Xf8T, yT8, Wbf, bvec, dInv, yAll);
    layers_kernel<1><<<768, 256, 0, stream>>>(adjF8, Xf8T, yT8, Wbf, bvec, dInv, yAll);
    final_kernel<<<512, 256, 0, stream>>>(yAll, WoutBf, gcn, bout, out);
}